// Round 3
// baseline (1445.223 us; speedup 1.0000x reference)
//
#include <hip/hip_runtime.h>
#include <hip/hip_bf16.h>

#define NPTS 65536
#define NSAMP 16
#define CH 256
#define CNT (NPTS * NSAMP)   // 1048576
#define EPSV 1e-5f

typedef __hip_bfloat16 bf16;
typedef __attribute__((ext_vector_type(8))) short short8;
typedef __attribute__((ext_vector_type(4))) float floatx4;

__device__ __forceinline__ float b2f(bf16 v) { return __bfloat162float(v); }

__device__ __forceinline__ short f2bf_bits(float f) {
    bf16 h = __float2bfloat16(f);
    short s;
    __builtin_memcpy(&s, &h, 2);
    return s;
}

// load 8 contiguous f32 -> bf16 MFMA fragment
__device__ __forceinline__ short8 ldfrag_f32(const float* p) {
    short8 r;
#pragma unroll
    for (int i = 0; i < 8; i++) r[i] = f2bf_bits(p[i]);
    return r;
}

// ---------------------------------------------------------------------------
// K1: projections  xq/xk/xv = x @ W^T + b   (MFMA 16x16x32 bf16)
// block = 256 thr = 4 waves; each wave computes a 16(M) x 256(N) strip.
// ---------------------------------------------------------------------------
__global__ __launch_bounds__(256) void proj_kernel(
    const float* __restrict__ x,
    const float* __restrict__ wq, const float* __restrict__ bq,
    const float* __restrict__ wk, const float* __restrict__ bk,
    const float* __restrict__ wv, const float* __restrict__ bv,
    bf16* __restrict__ xq, bf16* __restrict__ xk, bf16* __restrict__ xv)
{
    int z = blockIdx.y;
    const float* W = (z == 0) ? wq : (z == 1) ? wk : wv;
    const float* B = (z == 0) ? bq : (z == 1) ? bk : bv;
    bf16* O        = (z == 0) ? xq : (z == 1) ? xk : xv;

    int lane = threadIdx.x & 63;
    int wave = threadIdx.x >> 6;
    int m0 = blockIdx.x * 64 + wave * 16;
    int m = lane & 15;          // A row / B col within tile
    int q = lane >> 4;          // k-quad

    floatx4 acc[16];
#pragma unroll
    for (int nt = 0; nt < 16; nt++) acc[nt] = (floatx4){0.f, 0.f, 0.f, 0.f};

    for (int kk = 0; kk < CH; kk += 32) {
        short8 a = ldfrag_f32(x + (size_t)(m0 + m) * CH + kk + q * 8);
#pragma unroll
        for (int nt = 0; nt < 16; nt++) {
            short8 b = ldfrag_f32(W + (size_t)(nt * 16 + m) * CH + kk + q * 8);
            acc[nt] = __builtin_amdgcn_mfma_f32_16x16x32_bf16(a, b, acc[nt], 0, 0, 0);
        }
    }
    // C/D layout (verified m89): col = lane&15, row = (lane>>4)*4 + reg
    int rbase = q * 4;
#pragma unroll
    for (int nt = 0; nt < 16; nt++) {
        int col = nt * 16 + m;
        float bias = B[col];
#pragma unroll
        for (int i = 0; i < 4; i++) {
            O[(size_t)(m0 + rbase + i) * CH + col] = __float2bfloat16(acc[nt][i] + bias);
        }
    }
}

// ---------------------------------------------------------------------------
// K2: stats for BN_p over p_r1 = (p[idx]-p) @ wp1^T + bp1   (3 channels)
// ---------------------------------------------------------------------------
__global__ __launch_bounds__(256) void statsp_kernel(
    const float* __restrict__ p, const int* __restrict__ idx,
    const float* __restrict__ wp1, const float* __restrict__ bp1,
    float* __restrict__ statsP)
{
    float W00 = wp1[0], W01 = wp1[1], W02 = wp1[2];
    float W10 = wp1[3], W11 = wp1[4], W12 = wp1[5];
    float W20 = wp1[6], W21 = wp1[7], W22 = wp1[8];
    float B0 = bp1[0], B1 = bp1[1], B2 = bp1[2];

    float s0 = 0, s1 = 0, s2 = 0, q0 = 0, q1 = 0, q2 = 0;
    int stride = gridDim.x * blockDim.x;
    for (int r = blockIdx.x * blockDim.x + threadIdx.x; r < CNT; r += stride) {
        int n = r >> 4;
        int i = idx[r];
        float a0 = p[3 * (size_t)i]     - p[3 * (size_t)n];
        float a1 = p[3 * (size_t)i + 1] - p[3 * (size_t)n + 1];
        float a2 = p[3 * (size_t)i + 2] - p[3 * (size_t)n + 2];
        float v0 = W00 * a0 + W01 * a1 + W02 * a2 + B0;
        float v1 = W10 * a0 + W11 * a1 + W12 * a2 + B1;
        float v2 = W20 * a0 + W21 * a1 + W22 * a2 + B2;
        s0 += v0; q0 += v0 * v0;
        s1 += v1; q1 += v1 * v1;
        s2 += v2; q2 += v2 * v2;
    }
    float v[6] = {s0, s1, s2, q0, q1, q2};
#pragma unroll
    for (int k = 0; k < 6; k++) {
        float xv = v[k];
#pragma unroll
        for (int off = 32; off > 0; off >>= 1) xv += __shfl_down(xv, off);
        if ((threadIdx.x & 63) == 0) atomicAdd(&statsP[k], xv);
    }
}

// ---------------------------------------------------------------------------
// finalize: mean/var -> scale/shift   (ss[c] = scale, ss[nch+c] = shift)
// ---------------------------------------------------------------------------
__global__ void finalize_kernel(const float* __restrict__ stats,
                                const float* __restrict__ gamma,
                                const float* __restrict__ beta,
                                float* __restrict__ ss, int nch)
{
    int c = threadIdx.x;
    if (c < nch) {
        float inv = 1.0f / (float)CNT;
        float mean = stats[c] * inv;
        float var = stats[nch + c] * inv - mean * mean;
        float sc = gamma[c] * rsqrtf(var + EPSV);
        ss[c] = sc;
        ss[nch + c] = beta[c] - mean * sc;
    }
}

// ---------------------------------------------------------------------------
// K2b: r4[r] = relu(BN_p(p_r1)) as float4   [CNT]
// ---------------------------------------------------------------------------
__global__ __launch_bounds__(256) void computer_kernel(
    const float* __restrict__ p, const int* __restrict__ idx,
    const float* __restrict__ wp1, const float* __restrict__ bp1,
    const float* __restrict__ ssP, float4* __restrict__ r4)
{
    float W00 = wp1[0], W01 = wp1[1], W02 = wp1[2];
    float W10 = wp1[3], W11 = wp1[4], W12 = wp1[5];
    float W20 = wp1[6], W21 = wp1[7], W22 = wp1[8];
    float B0 = bp1[0], B1 = bp1[1], B2 = bp1[2];
    float sc0 = ssP[0], sc1 = ssP[1], sc2 = ssP[2];
    float sh0 = ssP[3], sh1 = ssP[4], sh2 = ssP[5];

    int stride = gridDim.x * blockDim.x;
    for (int r = blockIdx.x * blockDim.x + threadIdx.x; r < CNT; r += stride) {
        int n = r >> 4;
        int i = idx[r];
        float a0 = p[3 * (size_t)i]     - p[3 * (size_t)n];
        float a1 = p[3 * (size_t)i + 1] - p[3 * (size_t)n + 1];
        float a2 = p[3 * (size_t)i + 2] - p[3 * (size_t)n + 2];
        float v0 = fmaxf(sc0 * (W00 * a0 + W01 * a1 + W02 * a2 + B0) + sh0, 0.f);
        float v1 = fmaxf(sc1 * (W10 * a0 + W11 * a1 + W12 * a2 + B1) + sh1, 0.f);
        float v2 = fmaxf(sc2 * (W20 * a0 + W21 * a1 + W22 * a2 + B2) + sh2, 0.f);
        r4[r] = make_float4(v0, v1, v2, 0.f);
    }
}

// ---------------------------------------------------------------------------
// K3: stats for BN1 over w = xk[idx] - xq + p_r2   (256 channels)
// ---------------------------------------------------------------------------
__global__ __launch_bounds__(256) void stats1_kernel(
    const int* __restrict__ idx, const float4* __restrict__ r4,
    const bf16* __restrict__ xk, const bf16* __restrict__ xq,
    const float* __restrict__ wp2, const float* __restrict__ bp2,
    float* __restrict__ stats1)
{
    int c = threadIdx.x;
    float w0 = wp2[3 * c], w1 = wp2[3 * c + 1], w2 = wp2[3 * c + 2];
    float bc = bp2[c];
    float sum = 0, sq = 0;
    int r0 = blockIdx.x * 1024;
#pragma unroll 4
    for (int rr = 0; rr < 1024; rr++) {
        int r = r0 + rr;
        int i = idx[r];
        float4 rv = r4[r];
        float pr2 = rv.x * w0 + rv.y * w1 + rv.z * w2 + bc;
        float w = b2f(xk[(size_t)i * CH + c]) - b2f(xq[(size_t)(r >> 4) * CH + c]) + pr2;
        sum += w; sq += w * w;
    }
    atomicAdd(&stats1[c], sum);
    atomicAdd(&stats1[CH + c], sq);
}

// ---------------------------------------------------------------------------
// K4: y2 = relu(BN1(w)) @ ww1^T + bw1 (bf16) + stats for BN2 (32 ch)
// ---------------------------------------------------------------------------
__global__ __launch_bounds__(256) void stats2_kernel(
    const int* __restrict__ idx, const float4* __restrict__ r4,
    const bf16* __restrict__ xk, const bf16* __restrict__ xq,
    const float* __restrict__ wp2, const float* __restrict__ bp2,
    const float* __restrict__ ss1,
    const float* __restrict__ ww1, const float* __restrict__ bw1,
    bf16* __restrict__ y2, float* __restrict__ stats2)
{
    __shared__ __align__(16) bf16 hb[64 * 264];   // 64 rows, stride 264 (+8 pad)

    int t = threadIdx.x;
    int lane = t & 63, wave = t >> 6;
    int m = lane & 15, q = lane >> 4;

    int c = t;
    float w0 = wp2[3 * c], w1 = wp2[3 * c + 1], w2 = wp2[3 * c + 2];
    float bc = bp2[c];
    float s1c = ss1[c], t1c = ss1[CH + c];

    // ww1 B-fragments in registers: [k-step][n-tile]
    short8 bfrag[8][2];
#pragma unroll
    for (int k = 0; k < 8; k++)
#pragma unroll
        for (int nt = 0; nt < 2; nt++)
            bfrag[k][nt] = ldfrag_f32(ww1 + (size_t)(nt * 16 + m) * CH + k * 32 + q * 8);
    float bw0 = bw1[m], bw16 = bw1[16 + m];

    float jsum0 = 0, jsum1 = 0, jsq0 = 0, jsq1 = 0;
    int rbase0 = blockIdx.x * 1024;

    for (int it = 0; it < 16; it++) {
        int rb = rbase0 + it * 64;
        for (int rr = 0; rr < 64; rr++) {
            int r = rb + rr;
            int i = idx[r];
            float4 rv = r4[r];
            float pr2 = rv.x * w0 + rv.y * w1 + rv.z * w2 + bc;
            float w = b2f(xk[(size_t)i * CH + c]) - b2f(xq[(size_t)(r >> 4) * CH + c]) + pr2;
            hb[rr * 264 + c] = __float2bfloat16(fmaxf(s1c * w + t1c, 0.f));
        }
        __syncthreads();
        floatx4 a0 = (floatx4){0.f, 0.f, 0.f, 0.f};
        floatx4 a1 = (floatx4){0.f, 0.f, 0.f, 0.f};
        const bf16* abase = hb + (wave * 16 + m) * 264 + q * 8;
#pragma unroll
        for (int k = 0; k < 8; k++) {
            short8 af = *(const short8*)(abase + k * 32);
            a0 = __builtin_amdgcn_mfma_f32_16x16x32_bf16(af, bfrag[k][0], a0, 0, 0, 0);
            a1 = __builtin_amdgcn_mfma_f32_16x16x32_bf16(af, bfrag[k][1], a1, 0, 0, 0);
        }
        int grow = rb + wave * 16 + q * 4;
#pragma unroll
        for (int ii = 0; ii < 4; ii++) {
            float y0 = a0[ii] + bw0;
            float y1 = a1[ii] + bw16;
            jsum0 += y0; jsq0 += y0 * y0;
            jsum1 += y1; jsq1 += y1 * y1;
            y2[(size_t)(grow + ii) * 32 + m]      = __float2bfloat16(y0);
            y2[(size_t)(grow + ii) * 32 + 16 + m] = __float2bfloat16(y1);
        }
        __syncthreads();
    }
    jsum0 += __shfl_xor(jsum0, 16); jsum0 += __shfl_xor(jsum0, 32);
    jsum1 += __shfl_xor(jsum1, 16); jsum1 += __shfl_xor(jsum1, 32);
    jsq0  += __shfl_xor(jsq0, 16);  jsq0  += __shfl_xor(jsq0, 32);
    jsq1  += __shfl_xor(jsq1, 16);  jsq1  += __shfl_xor(jsq1, 32);
    if (q == 0) {
        atomicAdd(&stats2[m], jsum0);
        atomicAdd(&stats2[16 + m], jsum1);
        atomicAdd(&stats2[32 + m], jsq0);
        atomicAdd(&stats2[48 + m], jsq1);
    }
}

// ---------------------------------------------------------------------------
// K5: per point: bn2 -> relu -> @ww2^T + bw2 -> softmax(s) -> weighted sum
// Output is FLOAT32 (reference returns f32; harness reads f32).
// ---------------------------------------------------------------------------
__global__ __launch_bounds__(256) void final_kernel(
    const int* __restrict__ idx, const float4* __restrict__ r4,
    const bf16* __restrict__ xv,
    const float* __restrict__ wp2, const float* __restrict__ bp2,
    const bf16* __restrict__ y2, const float* __restrict__ ss2,
    const float* __restrict__ ww2, const float* __restrict__ bw2,
    float* __restrict__ out)
{
    __shared__ float zb[16 * 33];
    __shared__ float lb[16 * 33];
    __shared__ float ww2l[32 * 33];
    __shared__ float rr[16][4];
    __shared__ int ib[16];

    int n = blockIdx.x, t = threadIdx.x;

    for (int e = t; e < 1024; e += 256)
        ww2l[(e >> 5) * 33 + (e & 31)] = ww2[e];
    if (t < 16) {
        ib[t] = idx[n * 16 + t];
        float4 v = r4[n * 16 + t];
        rr[t][0] = v.x; rr[t][1] = v.y; rr[t][2] = v.z;
    }
    __syncthreads();

    int j = t & 31, g = t >> 5;
    float s2j = ss2[j], t2j = ss2[32 + j];
    for (int s = g; s < 16; s += 8) {
        float y = b2f(y2[(size_t)(n * 16 + s) * 32 + j]);
        zb[s * 33 + j] = fmaxf(s2j * y + t2j, 0.f);
    }
    __syncthreads();
    float bwj = bw2[j];
    for (int s = g; s < 16; s += 8) {
        float lo = bwj;
#pragma unroll
        for (int u = 0; u < 32; u++) lo += zb[s * 33 + u] * ww2l[j * 33 + u];
        lb[s * 33 + j] = lo;
    }
    __syncthreads();
    if (t < 32) {
        float mx = -1e30f;
        for (int s = 0; s < 16; s++) mx = fmaxf(mx, lb[s * 33 + t]);
        float sum = 0.f;
        for (int s = 0; s < 16; s++) {
            float ev = __expf(lb[s * 33 + t] - mx);
            lb[s * 33 + t] = ev; sum += ev;
        }
        float inv = 1.f / sum;
        for (int s = 0; s < 16; s++) lb[s * 33 + t] *= inv;
    }
    __syncthreads();
    int c = t;
    float w0 = wp2[3 * c], w1 = wp2[3 * c + 1], w2 = wp2[3 * c + 2];
    float bc = bp2[c];
    float acc = 0.f;
#pragma unroll 4
    for (int s = 0; s < 16; s++) {
        int i = ib[s];
        float pr2 = rr[s][0] * w0 + rr[s][1] * w1 + rr[s][2] * w2 + bc;
        float v = b2f(xv[(size_t)i * CH + c]) + pr2;
        acc += v * lb[s * 33 + (c & 31)];
    }
    out[(size_t)n * CH + c] = acc;
}

// ---------------------------------------------------------------------------
extern "C" void kernel_launch(void* const* d_in, const int* in_sizes, int n_in,
                              void* d_out, int out_size, void* d_ws, size_t ws_size,
                              hipStream_t stream) {
    (void)in_sizes; (void)n_in; (void)out_size; (void)ws_size;

    const float* p   = (const float*)d_in[0];
    const float* x   = (const float*)d_in[1];
    const int*   idx = (const int*)d_in[2];
    const float* wq  = (const float*)d_in[3];  const float* bq  = (const float*)d_in[4];
    const float* wk  = (const float*)d_in[5];  const float* bk  = (const float*)d_in[6];
    const float* wv  = (const float*)d_in[7];  const float* bv  = (const float*)d_in[8];
    const float* wp1 = (const float*)d_in[9];  const float* bp1 = (const float*)d_in[10];
    const float* gp  = (const float*)d_in[11]; const float* btp = (const float*)d_in[12];
    const float* wp2 = (const float*)d_in[13]; const float* bp2 = (const float*)d_in[14];
    const float* g1  = (const float*)d_in[15]; const float* b1  = (const float*)d_in[16];
    const float* ww1 = (const float*)d_in[17]; const float* bw1 = (const float*)d_in[18];
    const float* g2  = (const float*)d_in[19]; const float* b2  = (const float*)d_in[20];
    const float* ww2 = (const float*)d_in[21]; const float* bw2 = (const float*)d_in[22];
    float* out = (float*)d_out;

    // workspace layout
    float* fws    = (float*)d_ws;
    float* statsP = fws;            // 6  (8 slots)
    float* ssP    = fws + 8;        // 6  (8 slots)
    float* stats1 = fws + 16;       // 512
    float* ss1    = fws + 528;      // 512
    float* stats2 = fws + 1040;     // 64
    float* ss2    = fws + 1104;     // 64
    char* big = (char*)d_ws + 8192;
    bf16* xq = (bf16*)big;
    bf16* xk = xq + (size_t)NPTS * CH;
    bf16* xv = xk + (size_t)NPTS * CH;
    bf16* y2 = xv + (size_t)NPTS * CH;                 // CNT*32 bf16
    float4* r4 = (float4*)(y2 + (size_t)CNT * 32);     // CNT float4

    hipMemsetAsync(d_ws, 0, 8192, stream);

    proj_kernel<<<dim3(NPTS / 64, 3), 256, 0, stream>>>(x, wq, bq, wk, bk, wv, bv, xq, xk, xv);
    statsp_kernel<<<512, 256, 0, stream>>>(p, idx, wp1, bp1, statsP);
    finalize_kernel<<<1, 256, 0, stream>>>(statsP, gp, btp, ssP, 3);
    computer_kernel<<<1024, 256, 0, stream>>>(p, idx, wp1, bp1, ssP, r4);
    stats1_kernel<<<1024, 256, 0, stream>>>(idx, r4, xk, xq, wp2, bp2, stats1);
    finalize_kernel<<<1, 256, 0, stream>>>(stats1, g1, b1, ss1, 256);
    stats2_kernel<<<1024, 256, 0, stream>>>(idx, r4, xk, xq, wp2, bp2, ss1, ww1, bw1, y2, stats2);
    finalize_kernel<<<1, 256, 0, stream>>>(stats2, g2, b2, ss2, 32);
    final_kernel<<<NPTS, 256, 0, stream>>>(idx, r4, xv, wp2, bp2, y2, ss2, ww2, bw2, out);
}

// Round 4
// 919.090 us; speedup vs baseline: 1.5724x; 1.5724x over previous
//
#include <hip/hip_runtime.h>
#include <hip/hip_bf16.h>

#define NPTS 65536
#define NSAMP 16
#define CH 256
#define CNT (NPTS * NSAMP)   // 1048576
#define EPSV 1e-5f

typedef __hip_bfloat16 bf16;
typedef __attribute__((ext_vector_type(8))) short short8;
typedef __attribute__((ext_vector_type(4))) float floatx4;

__device__ __forceinline__ float b2f(bf16 v) { return __bfloat162float(v); }

// bf16 bits (as short) -> float
__device__ __forceinline__ float s2f(short v) {
    return __uint_as_float(((unsigned)(unsigned short)v) << 16);
}

__device__ __forceinline__ short f2bf_bits(float f) {
    bf16 h = __float2bfloat16(f);
    short s;
    __builtin_memcpy(&s, &h, 2);
    return s;
}

// ---------------------------------------------------------------------------
// convw: pack wq|wk|wv (f32) into Wcat[768*256] bf16
// ---------------------------------------------------------------------------
__global__ __launch_bounds__(256) void convw_kernel(
    const float* __restrict__ wq, const float* __restrict__ wk,
    const float* __restrict__ wv, bf16* __restrict__ Wcat)
{
    int e = (blockIdx.x * 256 + threadIdx.x) * 8;   // e < 196608
    const float* src = (e < 65536) ? wq : (e < 131072) ? wk : wv;
    int off = e & 65535;
    float4 f0 = *(const float4*)(src + off);
    float4 f1 = *(const float4*)(src + off + 4);
    short8 r;
    r[0] = f2bf_bits(f0.x); r[1] = f2bf_bits(f0.y);
    r[2] = f2bf_bits(f0.z); r[3] = f2bf_bits(f0.w);
    r[4] = f2bf_bits(f1.x); r[5] = f2bf_bits(f1.y);
    r[6] = f2bf_bits(f1.z); r[7] = f2bf_bits(f1.w);
    *(short8*)(Wcat + e) = r;
}

// ---------------------------------------------------------------------------
// gemm: C[65536 x 768] = x(f32) @ Wcat^T, written as xq|xk|xv bf16 slices.
// 128x128 tiles, BK=32, LDS stride 40 (pad), 4 waves each 64x64.
// ---------------------------------------------------------------------------
__global__ __launch_bounds__(256) void gemm_kernel(
    const float* __restrict__ x, const bf16* __restrict__ Wcat,
    const float* __restrict__ bq, const float* __restrict__ bk,
    const float* __restrict__ bv,
    bf16* __restrict__ xq, bf16* __restrict__ xk, bf16* __restrict__ xv)
{
    __shared__ __align__(16) bf16 As[128 * 40];
    __shared__ __align__(16) bf16 Bs[128 * 40];

    int t = threadIdx.x, lane = t & 63, wave = t >> 6;
    int m0 = blockIdx.x * 128;
    int y = blockIdx.y, n0 = y * 128;
    int srow = t >> 1, sch = t & 1;       // staging: 2 threads per row, 16 elems each
    int m = lane & 15, q = lane >> 4;
    int wm = wave >> 1, wn = wave & 1;

    floatx4 acc[4][4];
#pragma unroll
    for (int a = 0; a < 4; a++)
#pragma unroll
        for (int b = 0; b < 4; b++) acc[a][b] = (floatx4){0.f, 0.f, 0.f, 0.f};

    for (int kk = 0; kk < 256; kk += 32) {
        // stage A (f32 -> bf16)
        const float* ap = x + (size_t)(m0 + srow) * 256 + kk + sch * 16;
        float4 a0 = *(const float4*)(ap);
        float4 a1 = *(const float4*)(ap + 4);
        float4 a2 = *(const float4*)(ap + 8);
        float4 a3 = *(const float4*)(ap + 12);
        short8 h0, h1;
        h0[0] = f2bf_bits(a0.x); h0[1] = f2bf_bits(a0.y);
        h0[2] = f2bf_bits(a0.z); h0[3] = f2bf_bits(a0.w);
        h0[4] = f2bf_bits(a1.x); h0[5] = f2bf_bits(a1.y);
        h0[6] = f2bf_bits(a1.z); h0[7] = f2bf_bits(a1.w);
        h1[0] = f2bf_bits(a2.x); h1[1] = f2bf_bits(a2.y);
        h1[2] = f2bf_bits(a2.z); h1[3] = f2bf_bits(a2.w);
        h1[4] = f2bf_bits(a3.x); h1[5] = f2bf_bits(a3.y);
        h1[6] = f2bf_bits(a3.z); h1[7] = f2bf_bits(a3.w);
        *(short8*)&As[srow * 40 + sch * 16]     = h0;
        *(short8*)&As[srow * 40 + sch * 16 + 8] = h1;
        // stage B (bf16 copy)
        const bf16* bp = Wcat + (size_t)(n0 + srow) * 256 + kk + sch * 16;
        *(short8*)&Bs[srow * 40 + sch * 16]     = *(const short8*)bp;
        *(short8*)&Bs[srow * 40 + sch * 16 + 8] = *(const short8*)(bp + 8);
        __syncthreads();

        short8 av[4], bvv[4];
#pragma unroll
        for (int mt = 0; mt < 4; mt++)
            av[mt] = *(const short8*)&As[(wm * 64 + mt * 16 + m) * 40 + q * 8];
#pragma unroll
        for (int nt = 0; nt < 4; nt++)
            bvv[nt] = *(const short8*)&Bs[(wn * 64 + nt * 16 + m) * 40 + q * 8];
#pragma unroll
        for (int mt = 0; mt < 4; mt++)
#pragma unroll
            for (int nt = 0; nt < 4; nt++)
                acc[mt][nt] = __builtin_amdgcn_mfma_f32_16x16x32_bf16(av[mt], bvv[nt], acc[mt][nt], 0, 0, 0);
        __syncthreads();
    }

    int z = y >> 1;
    bf16* O        = (z == 0) ? xq : (z == 1) ? xk : xv;
    const float* B = (z == 0) ? bq : (z == 1) ? bk : bv;
    int cbase = (y & 1) * 128 + wn * 64;
#pragma unroll
    for (int nt = 0; nt < 4; nt++) {
        int oc = cbase + nt * 16 + m;
        float bias = B[oc];
#pragma unroll
        for (int mt = 0; mt < 4; mt++) {
            int grow = m0 + wm * 64 + mt * 16 + q * 4;
#pragma unroll
            for (int i = 0; i < 4; i++)
                O[(size_t)(grow + i) * 256 + oc] = __float2bfloat16(acc[mt][nt][i] + bias);
        }
    }
}

// ---------------------------------------------------------------------------
// statsp: BN_p stats over p_r1 = (p[idx]-p) @ wp1^T + bp1   (3 channels)
// ---------------------------------------------------------------------------
__global__ __launch_bounds__(256) void statsp_kernel(
    const float* __restrict__ p, const int* __restrict__ idx,
    const float* __restrict__ wp1, const float* __restrict__ bp1,
    float* __restrict__ statsP)
{
    float W00 = wp1[0], W01 = wp1[1], W02 = wp1[2];
    float W10 = wp1[3], W11 = wp1[4], W12 = wp1[5];
    float W20 = wp1[6], W21 = wp1[7], W22 = wp1[8];
    float B0 = bp1[0], B1 = bp1[1], B2 = bp1[2];

    float s0 = 0, s1 = 0, s2 = 0, q0 = 0, q1 = 0, q2 = 0;
    int stride = gridDim.x * blockDim.x;
    for (int r = blockIdx.x * blockDim.x + threadIdx.x; r < CNT; r += stride) {
        int n = r >> 4;
        int i = idx[r];
        float a0 = p[3 * (size_t)i]     - p[3 * (size_t)n];
        float a1 = p[3 * (size_t)i + 1] - p[3 * (size_t)n + 1];
        float a2 = p[3 * (size_t)i + 2] - p[3 * (size_t)n + 2];
        float v0 = W00 * a0 + W01 * a1 + W02 * a2 + B0;
        float v1 = W10 * a0 + W11 * a1 + W12 * a2 + B1;
        float v2 = W20 * a0 + W21 * a1 + W22 * a2 + B2;
        s0 += v0; q0 += v0 * v0;
        s1 += v1; q1 += v1 * v1;
        s2 += v2; q2 += v2 * v2;
    }
    float v[6] = {s0, s1, s2, q0, q1, q2};
#pragma unroll
    for (int k = 0; k < 6; k++) {
        float xv = v[k];
#pragma unroll
        for (int off = 32; off > 0; off >>= 1) xv += __shfl_down(xv, off);
        if ((threadIdx.x & 63) == 0) atomicAdd(&statsP[k], xv);
    }
}

// ---------------------------------------------------------------------------
// finalize: mean/var -> scale/shift
// ---------------------------------------------------------------------------
__global__ void finalize_kernel(const float* __restrict__ stats,
                                const float* __restrict__ gamma,
                                const float* __restrict__ beta,
                                float* __restrict__ ss, int nch)
{
    int c = threadIdx.x;
    if (c < nch) {
        float inv = 1.0f / (float)CNT;
        float mean = stats[c] * inv;
        float var = stats[nch + c] * inv - mean * mean;
        float sc = gamma[c] * rsqrtf(var + EPSV);
        ss[c] = sc;
        ss[nch + c] = beta[c] - mean * sc;
    }
}

// ---------------------------------------------------------------------------
// computer: r4[r] = relu(BN_p(p_r1)) as float4
// ---------------------------------------------------------------------------
__global__ __launch_bounds__(256) void computer_kernel(
    const float* __restrict__ p, const int* __restrict__ idx,
    const float* __restrict__ wp1, const float* __restrict__ bp1,
    const float* __restrict__ ssP, float4* __restrict__ r4)
{
    float W00 = wp1[0], W01 = wp1[1], W02 = wp1[2];
    float W10 = wp1[3], W11 = wp1[4], W12 = wp1[5];
    float W20 = wp1[6], W21 = wp1[7], W22 = wp1[8];
    float B0 = bp1[0], B1 = bp1[1], B2 = bp1[2];
    float sc0 = ssP[0], sc1 = ssP[1], sc2 = ssP[2];
    float sh0 = ssP[3], sh1 = ssP[4], sh2 = ssP[5];

    int stride = gridDim.x * blockDim.x;
    for (int r = blockIdx.x * blockDim.x + threadIdx.x; r < CNT; r += stride) {
        int n = r >> 4;
        int i = idx[r];
        float a0 = p[3 * (size_t)i]     - p[3 * (size_t)n];
        float a1 = p[3 * (size_t)i + 1] - p[3 * (size_t)n + 1];
        float a2 = p[3 * (size_t)i + 2] - p[3 * (size_t)n + 2];
        float v0 = fmaxf(sc0 * (W00 * a0 + W01 * a1 + W02 * a2 + B0) + sh0, 0.f);
        float v1 = fmaxf(sc1 * (W10 * a0 + W11 * a1 + W12 * a2 + B1) + sh1, 0.f);
        float v2 = fmaxf(sc2 * (W20 * a0 + W21 * a1 + W22 * a2 + B2) + sh2, 0.f);
        r4[r] = make_float4(v0, v1, v2, 0.f);
    }
}

// ---------------------------------------------------------------------------
// stats1: BN1 stats over w = xk[idx] - xq + p_r2.  Thread = 8 channels,
// short8 gathers, LDS block-reduce, 2 atomics/thread-channel.
// ---------------------------------------------------------------------------
__global__ __launch_bounds__(256) void stats1_kernel(
    const int* __restrict__ idx, const float4* __restrict__ r4,
    const bf16* __restrict__ xk, const bf16* __restrict__ xq,
    const float* __restrict__ wp2, const float* __restrict__ bp2,
    float* __restrict__ stats1)
{
    __shared__ int idxs[1024];
    __shared__ float redS[8 * 264];
    __shared__ float redQ[8 * 264];

    int t = threadIdx.x;
    int r0 = blockIdx.x * 1024;
    for (int e = t; e < 1024; e += 256) idxs[e] = idx[r0 + e];

    int sub = t & 31, rl = t >> 5, cb = sub * 8;
    float w0[8], w1[8], w2[8], bc[8];
#pragma unroll
    for (int k = 0; k < 8; k++) {
        w0[k] = wp2[3 * (cb + k)];
        w1[k] = wp2[3 * (cb + k) + 1];
        w2[k] = wp2[3 * (cb + k) + 2];
        bc[k] = bp2[cb + k];
    }
    float s8[8] = {0, 0, 0, 0, 0, 0, 0, 0};
    float q8[8] = {0, 0, 0, 0, 0, 0, 0, 0};
    __syncthreads();

#pragma unroll 4
    for (int rr = rl; rr < 1024; rr += 8) {
        int r = r0 + rr;
        int i = idxs[rr];
        float4 rv = r4[r];
        short8 kv = *(const short8*)(xk + (size_t)i * 256 + cb);
        short8 qv = *(const short8*)(xq + (size_t)(r >> 4) * 256 + cb);
#pragma unroll
        for (int k = 0; k < 8; k++) {
            float w = s2f(kv[k]) - s2f(qv[k]) + rv.x * w0[k] + rv.y * w1[k] + rv.z * w2[k] + bc[k];
            s8[k] += w; q8[k] += w * w;
        }
    }
#pragma unroll
    for (int k = 0; k < 8; k++) {
        redS[rl * 264 + cb + k] = s8[k];
        redQ[rl * 264 + cb + k] = q8[k];
    }
    __syncthreads();
    int c = t;
    float ts = 0, tq = 0;
#pragma unroll
    for (int sr = 0; sr < 8; sr++) {
        ts += redS[sr * 264 + c];
        tq += redQ[sr * 264 + c];
    }
    atomicAdd(&stats1[c], ts);
    atomicAdd(&stats1[256 + c], tq);
}

// ---------------------------------------------------------------------------
// stats2: y2 = relu(BN1(w)) @ ww1^T + bw1 (bf16) + BN2 stats.
// Phase1 vectorized (8ch/thread, short8); ww1 frags in padded LDS.
// ---------------------------------------------------------------------------
__global__ __launch_bounds__(256) void stats2_kernel(
    const int* __restrict__ idx, const float4* __restrict__ r4,
    const bf16* __restrict__ xk, const bf16* __restrict__ xq,
    const float* __restrict__ wp2, const float* __restrict__ bp2,
    const float* __restrict__ ss1,
    const float* __restrict__ ww1, const float* __restrict__ bw1,
    bf16* __restrict__ y2, float* __restrict__ stats2)
{
    __shared__ __align__(16) bf16 hb[64 * 264];    // h tile, stride 264
    __shared__ __align__(16) bf16 ws1[32 * 264];   // ww1 bf16, stride 264
    __shared__ int idxs[1024];

    int t = threadIdx.x;
    int lane = t & 63, wave = t >> 6;
    int m = lane & 15, q = lane >> 4;
    int sub = t & 31, rl = t >> 5, cb = sub * 8;
    int r0 = blockIdx.x * 1024;

    // stage ww1 -> LDS (bf16) and idx chunk
    for (int e = t; e < 8192; e += 256)
        ws1[(e >> 8) * 264 + (e & 255)] = __float2bfloat16(ww1[e]);
    for (int e = t; e < 1024; e += 256) idxs[e] = idx[r0 + e];

    float w0[8], w1[8], w2[8], bc[8], s1c[8], t1c[8];
#pragma unroll
    for (int k = 0; k < 8; k++) {
        w0[k] = wp2[3 * (cb + k)];
        w1[k] = wp2[3 * (cb + k) + 1];
        w2[k] = wp2[3 * (cb + k) + 2];
        bc[k] = bp2[cb + k];
        s1c[k] = ss1[cb + k];
        t1c[k] = ss1[256 + cb + k];
    }
    float bw0 = bw1[m], bw16 = bw1[16 + m];
    float jsum0 = 0, jsum1 = 0, jsq0 = 0, jsq1 = 0;
    __syncthreads();

    for (int it = 0; it < 16; it++) {
        int rb = r0 + it * 64;
        // phase 1: 64 rows of h into LDS (8 rows x 32 ch-groups in parallel)
#pragma unroll 2
        for (int rr = rl; rr < 64; rr += 8) {
            int r = rb + rr;
            int i = idxs[it * 64 + rr];
            float4 rv = r4[r];
            short8 kv = *(const short8*)(xk + (size_t)i * 256 + cb);
            short8 qv = *(const short8*)(xq + (size_t)(r >> 4) * 256 + cb);
            short8 h;
#pragma unroll
            for (int k = 0; k < 8; k++) {
                float w = s2f(kv[k]) - s2f(qv[k]) + rv.x * w0[k] + rv.y * w1[k] + rv.z * w2[k] + bc[k];
                h[k] = f2bf_bits(fmaxf(s1c[k] * w + t1c[k], 0.f));
            }
            *(short8*)&hb[rr * 264 + cb] = h;
        }
        __syncthreads();
        // phase 2: wave MFMAs rows [wave*16, wave*16+16)
        floatx4 a0 = (floatx4){0.f, 0.f, 0.f, 0.f};
        floatx4 a1 = (floatx4){0.f, 0.f, 0.f, 0.f};
        const bf16* abase = hb + (wave * 16 + m) * 264 + q * 8;
#pragma unroll
        for (int k = 0; k < 8; k++) {
            short8 af = *(const short8*)(abase + k * 32);
            short8 b0 = *(const short8*)&ws1[m * 264 + k * 32 + q * 8];
            short8 b1 = *(const short8*)&ws1[(16 + m) * 264 + k * 32 + q * 8];
            a0 = __builtin_amdgcn_mfma_f32_16x16x32_bf16(af, b0, a0, 0, 0, 0);
            a1 = __builtin_amdgcn_mfma_f32_16x16x32_bf16(af, b1, a1, 0, 0, 0);
        }
        int grow = rb + wave * 16 + q * 4;
#pragma unroll
        for (int ii = 0; ii < 4; ii++) {
            float y0 = a0[ii] + bw0;
            float y1 = a1[ii] + bw16;
            jsum0 += y0; jsq0 += y0 * y0;
            jsum1 += y1; jsq1 += y1 * y1;
            y2[(size_t)(grow + ii) * 32 + m]      = __float2bfloat16(y0);
            y2[(size_t)(grow + ii) * 32 + 16 + m] = __float2bfloat16(y1);
        }
        __syncthreads();
    }
    jsum0 += __shfl_xor(jsum0, 16); jsum0 += __shfl_xor(jsum0, 32);
    jsum1 += __shfl_xor(jsum1, 16); jsum1 += __shfl_xor(jsum1, 32);
    jsq0  += __shfl_xor(jsq0, 16);  jsq0  += __shfl_xor(jsq0, 32);
    jsq1  += __shfl_xor(jsq1, 16);  jsq1  += __shfl_xor(jsq1, 32);
    if (q == 0) {
        atomicAdd(&stats2[m], jsum0);
        atomicAdd(&stats2[16 + m], jsum1);
        atomicAdd(&stats2[32 + m], jsq0);
        atomicAdd(&stats2[48 + m], jsq1);
    }
}

// ---------------------------------------------------------------------------
// final: bn2 -> relu -> @ww2^T + bw2 -> softmax(s) -> weighted sum (f32 out)
// Phase D vectorized: 8 ch/thread short8 gathers + LDS reduction over s-groups.
// ---------------------------------------------------------------------------
__global__ __launch_bounds__(256) void final_kernel(
    const int* __restrict__ idx, const float4* __restrict__ r4,
    const bf16* __restrict__ xv,
    const float* __restrict__ wp2, const float* __restrict__ bp2,
    const bf16* __restrict__ y2, const float* __restrict__ ss2,
    const float* __restrict__ ww2, const float* __restrict__ bw2,
    float* __restrict__ out)
{
    __shared__ float zb[16 * 33];
    __shared__ float lb[16 * 33];
    __shared__ float ww2l[32 * 33];
    __shared__ float rr[16][4];
    __shared__ int ib[16];
    __shared__ float part[8 * 264];

    int n = blockIdx.x, t = threadIdx.x;

    for (int e = t; e < 1024; e += 256)
        ww2l[(e >> 5) * 33 + (e & 31)] = ww2[e];
    if (t < 16) {
        ib[t] = idx[n * 16 + t];
        float4 v = r4[n * 16 + t];
        rr[t][0] = v.x; rr[t][1] = v.y; rr[t][2] = v.z;
    }
    __syncthreads();

    int j = t & 31, g = t >> 5;
    float s2j = ss2[j], t2j = ss2[32 + j];
    for (int s = g; s < 16; s += 8) {
        float y = b2f(y2[(size_t)(n * 16 + s) * 32 + j]);
        zb[s * 33 + j] = fmaxf(s2j * y + t2j, 0.f);
    }
    __syncthreads();
    float bwj = bw2[j];
    for (int s = g; s < 16; s += 8) {
        float lo = bwj;
#pragma unroll
        for (int u = 0; u < 32; u++) lo += zb[s * 33 + u] * ww2l[j * 33 + u];
        lb[s * 33 + j] = lo;
    }
    __syncthreads();
    if (t < 32) {
        float mx = -1e30f;
        for (int s = 0; s < 16; s++) mx = fmaxf(mx, lb[s * 33 + t]);
        float sum = 0.f;
        for (int s = 0; s < 16; s++) {
            float ev = __expf(lb[s * 33 + t] - mx);
            lb[s * 33 + t] = ev; sum += ev;
        }
        float inv = 1.f / sum;
        for (int s = 0; s < 16; s++) lb[s * 33 + t] *= inv;
    }
    __syncthreads();

    // phase D: thread = 8 channels, 2 neighbors; LDS-reduce over 8 s-groups
    int sub = t & 31, srow = t >> 5, cb = sub * 8;
    float w0v[8], w1v[8], w2v[8], bcv[8];
#pragma unroll
    for (int k = 0; k < 8; k++) {
        w0v[k] = wp2[3 * (cb + k)];
        w1v[k] = wp2[3 * (cb + k) + 1];
        w2v[k] = wp2[3 * (cb + k) + 2];
        bcv[k] = bp2[cb + k];
    }
    float acc8[8] = {0, 0, 0, 0, 0, 0, 0, 0};
#pragma unroll
    for (int ss = 0; ss < 2; ss++) {
        int s = srow + ss * 8;
        int i = ib[s];
        short8 v = *(const short8*)(xv + (size_t)i * 256 + cb);
        float rx = rr[s][0], ry = rr[s][1], rz = rr[s][2];
#pragma unroll
        for (int k = 0; k < 8; k++) {
            float pr2 = rx * w0v[k] + ry * w1v[k] + rz * w2v[k] + bcv[k];
            float wsm = lb[s * 33 + ((cb + k) & 31)];
            acc8[k] += (s2f(v[k]) + pr2) * wsm;
        }
    }
#pragma unroll
    for (int k = 0; k < 8; k++) part[srow * 264 + cb + k] = acc8[k];
    __syncthreads();
    int c = t;
    float tot = 0;
#pragma unroll
    for (int sr = 0; sr < 8; sr++) tot += part[sr * 264 + c];
    out[(size_t)n * 256 + c] = tot;
}

// ---------------------------------------------------------------------------
extern "C" void kernel_launch(void* const* d_in, const int* in_sizes, int n_in,
                              void* d_out, int out_size, void* d_ws, size_t ws_size,
                              hipStream_t stream) {
    (void)in_sizes; (void)n_in; (void)out_size; (void)ws_size;

    const float* p   = (const float*)d_in[0];
    const float* x   = (const float*)d_in[1];
    const int*   idx = (const int*)d_in[2];
    const float* wq  = (const float*)d_in[3];  const float* bq  = (const float*)d_in[4];
    const float* wk  = (const float*)d_in[5];  const float* bk  = (const float*)d_in[6];
    const float* wv  = (const float*)d_in[7];  const float* bv  = (const float*)d_in[8];
    const float* wp1 = (const float*)d_in[9];  const float* bp1 = (const float*)d_in[10];
    const float* gp  = (const float*)d_in[11]; const float* btp = (const float*)d_in[12];
    const float* wp2 = (const float*)d_in[13]; const float* bp2 = (const float*)d_in[14];
    const float* g1  = (const float*)d_in[15]; const float* b1  = (const float*)d_in[16];
    const float* ww1 = (const float*)d_in[17]; const float* bw1 = (const float*)d_in[18];
    const float* g2  = (const float*)d_in[19]; const float* b2  = (const float*)d_in[20];
    const float* ww2 = (const float*)d_in[21]; const float* bw2 = (const float*)d_in[22];
    float* out = (float*)d_out;

    // workspace layout
    float* fws    = (float*)d_ws;
    float* statsP = fws;            // 6  (8 slots)
    float* ssP    = fws + 8;        // 6  (8 slots)
    float* stats1 = fws + 16;       // 512
    float* ss1    = fws + 528;      // 512
    float* stats2 = fws + 1040;     // 64
    float* ss2    = fws + 1104;     // 64
    bf16* Wcat = (bf16*)((char*)d_ws + 8192);          // 768*256 bf16 = 393216 B
    bf16* xq = (bf16*)((char*)d_ws + 401408);
    bf16* xk = xq + (size_t)NPTS * CH;
    bf16* xv = xk + (size_t)NPTS * CH;
    bf16* y2 = xv + (size_t)NPTS * CH;                 // CNT*32 bf16
    float4* r4 = (float4*)(y2 + (size_t)CNT * 32);     // CNT float4
    // total ~185 MB

    hipMemsetAsync(d_ws, 0, 8192, stream);

    convw_kernel<<<96, 256, 0, stream>>>(wq, wk, wv, Wcat);
    gemm_kernel<<<dim3(512, 6), 256, 0, stream>>>(x, Wcat, bq, bk, bv, xq, xk, xv);
    statsp_kernel<<<512, 256, 0, stream>>>(p, idx, wp1, bp1, statsP);
    finalize_kernel<<<1, 256, 0, stream>>>(statsP, gp, btp, ssP, 3);
    computer_kernel<<<1024, 256, 0, stream>>>(p, idx, wp1, bp1, ssP, r4);
    stats1_kernel<<<1024, 256, 0, stream>>>(idx, r4, xk, xq, wp2, bp2, stats1);
    finalize_kernel<<<1, 256, 0, stream>>>(stats1, g1, b1, ss1, 256);
    stats2_kernel<<<1024, 256, 0, stream>>>(idx, r4, xk, xq, wp2, bp2, ss1, ww1, bw1, y2, stats2);
    finalize_kernel<<<1, 256, 0, stream>>>(stats2, g2, b2, ss2, 32);
    final_kernel<<<NPTS, 256, 0, stream>>>(idx, r4, xv, wp2, bp2, y2, ss2, ww2, bw2, out);
}